// Round 1
// baseline (1544.884 us; speedup 1.0000x reference)
//
#include <hip/hip_runtime.h>

#define K_IN 256
#define N_OUT 64

// ---------------- GEMM: support[M][64] = x[M][256] @ W[256][64], fp32 -------
// 64x64 tile per block, BK=32, 256 threads, 4x4 acc per thread.
__global__ __launch_bounds__(256) void gemm_kernel(const float* __restrict__ x,
                                                   const float* __restrict__ w,
                                                   float* __restrict__ support,
                                                   int M) {
    __shared__ float At[32][68];   // A transposed: At[k][m], pad 64->68 (16B-aligned rows)
    __shared__ float Bs[32][64];   // B natural: Bs[k][n]

    const int tid = threadIdx.x;
    const int tx = tid & 15;    // n-quad index
    const int ty = tid >> 4;    // m-quad index
    const int m0 = blockIdx.x * 64;

    float acc[4][4] = {};

    const int lr = tid >> 3;         // 0..31
    const int lc = (tid & 7) * 4;    // 0,4,..,28

    for (int k0 = 0; k0 < K_IN; k0 += 32) {
        // stage A: rows m0..m0+63, k = k0..k0+31, transposed into At
        #pragma unroll
        for (int h = 0; h < 2; ++h) {
            int r = lr + h * 32;
            int gm = m0 + r;
            float4 v = make_float4(0.f, 0.f, 0.f, 0.f);
            if (gm < M)
                v = *reinterpret_cast<const float4*>(&x[(size_t)gm * K_IN + k0 + lc]);
            At[lc + 0][r] = v.x;
            At[lc + 1][r] = v.y;
            At[lc + 2][r] = v.z;
            At[lc + 3][r] = v.w;
        }
        // stage B: w[k0..k0+31][0..63]
        {
            int kb = tid >> 4;            // 0..15
            int nb = (tid & 15) * 4;
            *reinterpret_cast<float4*>(&Bs[kb][nb]) =
                *reinterpret_cast<const float4*>(&w[(size_t)(k0 + kb) * N_OUT + nb]);
            *reinterpret_cast<float4*>(&Bs[kb + 16][nb]) =
                *reinterpret_cast<const float4*>(&w[(size_t)(k0 + kb + 16) * N_OUT + nb]);
        }
        __syncthreads();
        #pragma unroll
        for (int kk = 0; kk < 32; ++kk) {
            float4 a4 = *reinterpret_cast<const float4*>(&At[kk][ty * 4]);
            float4 b4 = *reinterpret_cast<const float4*>(&Bs[kk][tx * 4]);
            float a[4] = {a4.x, a4.y, a4.z, a4.w};
            float b[4] = {b4.x, b4.y, b4.z, b4.w};
            #pragma unroll
            for (int i = 0; i < 4; ++i)
                #pragma unroll
                for (int j = 0; j < 4; ++j)
                    acc[i][j] = fmaf(a[i], b[j], acc[i][j]);
        }
        __syncthreads();
    }

    #pragma unroll
    for (int i = 0; i < 4; ++i) {
        int gm = m0 + ty * 4 + i;
        if (gm < M) {
            float4 v = make_float4(acc[i][0], acc[i][1], acc[i][2], acc[i][3]);
            *reinterpret_cast<float4*>(&support[(size_t)gm * N_OUT + tx * 4]) = v;
        }
    }
}

// ---------------- SpMM scatter: out[dst] += w_e * support[src] --------------
// 16 threads per edge; each thread owns 4 consecutive columns (float4 gather,
// 4 scalar f32 atomics).
__global__ __launch_bounds__(256) void scatter_kernel(const float* __restrict__ support,
                                                      const int* __restrict__ esrc,
                                                      const int* __restrict__ edst,
                                                      const float* __restrict__ ew,
                                                      float* __restrict__ out,
                                                      int E) {
    int tid = blockIdx.x * blockDim.x + threadIdx.x;
    int e = tid >> 4;
    if (e >= E) return;
    int c = (tid & 15) * 4;

    int s = esrc[e];
    int d = edst[e];
    float w = ew[e];

    float4 v = *reinterpret_cast<const float4*>(&support[(size_t)s * N_OUT + c]);
    float* o = &out[(size_t)d * N_OUT + c];
    atomicAdd(o + 0, v.x * w);
    atomicAdd(o + 1, v.y * w);
    atomicAdd(o + 2, v.z * w);
    atomicAdd(o + 3, v.w * w);
}

// ---------------- ReLU in place ---------------------------------------------
__global__ __launch_bounds__(256) void relu_kernel(float* __restrict__ out, int n4) {
    int i = blockIdx.x * blockDim.x + threadIdx.x;
    if (i < n4) {
        float4 v = reinterpret_cast<float4*>(out)[i];
        v.x = fmaxf(v.x, 0.f);
        v.y = fmaxf(v.y, 0.f);
        v.z = fmaxf(v.z, 0.f);
        v.w = fmaxf(v.w, 0.f);
        reinterpret_cast<float4*>(out)[i] = v;
    }
}

extern "C" void kernel_launch(void* const* d_in, const int* in_sizes, int n_in,
                              void* d_out, int out_size, void* d_ws, size_t ws_size,
                              hipStream_t stream) {
    const float* x    = (const float*)d_in[0];
    const float* w    = (const float*)d_in[1];
    const int*   esrc = (const int*)d_in[2];
    const int*   edst = (const int*)d_in[3];
    const float* ew   = (const float*)d_in[4];
    float* out = (float*)d_out;

    float* support = (float*)d_ws;           // M*64 f32 = 25.6 MB scratch

    const int M = in_sizes[0] / K_IN;        // 100000
    const int E = in_sizes[2];               // 1600000

    // zero the (poisoned) output accumulator
    hipMemsetAsync(d_out, 0, (size_t)out_size * sizeof(float), stream);

    // support = x @ W
    gemm_kernel<<<(M + 63) / 64, 256, 0, stream>>>(x, w, support, M);

    // scatter-add messages
    long long sthreads = (long long)E * 16;
    int sblocks = (int)((sthreads + 255) / 256);
    scatter_kernel<<<sblocks, 256, 0, stream>>>(support, esrc, edst, ew, out, E);

    // relu
    int n4 = out_size / 4;
    relu_kernel<<<(n4 + 255) / 256, 256, 0, stream>>>(out, n4);
}

// Round 2
// 420.090 us; speedup vs baseline: 3.6775x; 3.6775x over previous
//
#include <hip/hip_runtime.h>

#define K_IN 256
#define N_OUT 64

// ---------------- GEMM: support[M][64] = x[M][256] @ W[256][64], fp32 -------
__global__ __launch_bounds__(256) void gemm_kernel(const float* __restrict__ x,
                                                   const float* __restrict__ w,
                                                   float* __restrict__ support,
                                                   int M) {
    __shared__ float At[32][68];
    __shared__ float Bs[32][64];

    const int tid = threadIdx.x;
    const int tx = tid & 15;
    const int ty = tid >> 4;
    const int m0 = blockIdx.x * 64;

    float acc[4][4] = {};

    const int lr = tid >> 3;
    const int lc = (tid & 7) * 4;

    for (int k0 = 0; k0 < K_IN; k0 += 32) {
        #pragma unroll
        for (int h = 0; h < 2; ++h) {
            int r = lr + h * 32;
            int gm = m0 + r;
            float4 v = make_float4(0.f, 0.f, 0.f, 0.f);
            if (gm < M)
                v = *reinterpret_cast<const float4*>(&x[(size_t)gm * K_IN + k0 + lc]);
            At[lc + 0][r] = v.x;
            At[lc + 1][r] = v.y;
            At[lc + 2][r] = v.z;
            At[lc + 3][r] = v.w;
        }
        {
            int kb = tid >> 4;
            int nb = (tid & 15) * 4;
            *reinterpret_cast<float4*>(&Bs[kb][nb]) =
                *reinterpret_cast<const float4*>(&w[(size_t)(k0 + kb) * N_OUT + nb]);
            *reinterpret_cast<float4*>(&Bs[kb + 16][nb]) =
                *reinterpret_cast<const float4*>(&w[(size_t)(k0 + kb + 16) * N_OUT + nb]);
        }
        __syncthreads();
        #pragma unroll
        for (int kk = 0; kk < 32; ++kk) {
            float4 a4 = *reinterpret_cast<const float4*>(&At[kk][ty * 4]);
            float4 b4 = *reinterpret_cast<const float4*>(&Bs[kk][tx * 4]);
            float a[4] = {a4.x, a4.y, a4.z, a4.w};
            float b[4] = {b4.x, b4.y, b4.z, b4.w};
            #pragma unroll
            for (int i = 0; i < 4; ++i)
                #pragma unroll
                for (int j = 0; j < 4; ++j)
                    acc[i][j] = fmaf(a[i], b[j], acc[i][j]);
        }
        __syncthreads();
    }

    #pragma unroll
    for (int i = 0; i < 4; ++i) {
        int gm = m0 + ty * 4 + i;
        if (gm < M) {
            float4 v = make_float4(acc[i][0], acc[i][1], acc[i][2], acc[i][3]);
            *reinterpret_cast<float4*>(&support[(size_t)gm * N_OUT + tx * 4]) = v;
        }
    }
}

// ---------------- counting sort by dst --------------------------------------
__global__ __launch_bounds__(256) void hist_kernel(const int* __restrict__ edst,
                                                   int* __restrict__ counts, int E) {
    int i = blockIdx.x * blockDim.x + threadIdx.x;
    if (i < E) atomicAdd(&counts[edst[i]], 1);
}

// scan1: per-block (1024 elems) exclusive scan in place, block total -> bsum
__global__ __launch_bounds__(256) void scan1_kernel(int* __restrict__ data,
                                                    int* __restrict__ bsum, int M) {
    __shared__ int lds[256];
    int tid = threadIdx.x;
    int base = blockIdx.x * 1024 + tid * 4;
    int v[4];
    #pragma unroll
    for (int j = 0; j < 4; ++j) v[j] = (base + j < M) ? data[base + j] : 0;
    int s = v[0] + v[1] + v[2] + v[3];
    lds[tid] = s;
    __syncthreads();
    for (int off = 1; off < 256; off <<= 1) {
        int t = (tid >= off) ? lds[tid - off] : 0;
        __syncthreads();
        lds[tid] += t;
        __syncthreads();
    }
    int excl = lds[tid] - s;
    if (tid == 255) bsum[blockIdx.x] = lds[255];
    int run = excl;
    #pragma unroll
    for (int j = 0; j < 4; ++j) {
        if (base + j < M) data[base + j] = run;
        run += v[j];
    }
}

// scan2: exclusive scan of block sums (nb <= 256); grand total -> row_ptr[M]
__global__ __launch_bounds__(256) void scan2_kernel(int* __restrict__ bsum,
                                                    int* __restrict__ row_ptr_end, int nb) {
    __shared__ int lds[256];
    int tid = threadIdx.x;
    int v = (tid < nb) ? bsum[tid] : 0;
    lds[tid] = v;
    __syncthreads();
    for (int off = 1; off < 256; off <<= 1) {
        int t = (tid >= off) ? lds[tid - off] : 0;
        __syncthreads();
        lds[tid] += t;
        __syncthreads();
    }
    if (tid < nb) bsum[tid] = lds[tid] - v;
    if (tid == 255) *row_ptr_end = lds[255];
}

// scan3: add block offsets; also init cursor = row start
__global__ __launch_bounds__(256) void scan3_kernel(int* __restrict__ row_ptr,
                                                    int* __restrict__ cursor,
                                                    const int* __restrict__ bsum, int M) {
    int base = blockIdx.x * 1024 + threadIdx.x * 4;
    int add = bsum[blockIdx.x];
    #pragma unroll
    for (int j = 0; j < 4; ++j) {
        int i = base + j;
        if (i < M) {
            int r = row_ptr[i] + add;
            row_ptr[i] = r;
            cursor[i] = r;
        }
    }
}

// reorder edges into dst-grouped arrays
__global__ __launch_bounds__(256) void reorder_kernel(const int* __restrict__ esrc,
                                                      const int* __restrict__ edst,
                                                      const float* __restrict__ ew,
                                                      int* __restrict__ cursor,
                                                      int* __restrict__ ssrc,
                                                      float* __restrict__ sw, int E) {
    int i = blockIdx.x * blockDim.x + threadIdx.x;
    if (i >= E) return;
    int d = edst[i];
    int pos = atomicAdd(&cursor[d], 1);
    ssrc[pos] = esrc[i];
    sw[pos] = ew[i];
}

// ---------------- CSR accumulate + ReLU, 16 lanes per node ------------------
__global__ __launch_bounds__(256) void accum_kernel(const float* __restrict__ support,
                                                    const int* __restrict__ row_ptr,
                                                    const int* __restrict__ ssrc,
                                                    const float* __restrict__ sw,
                                                    float* __restrict__ out, int M) {
    int g = (blockIdx.x * blockDim.x + threadIdx.x) >> 4;   // node id
    if (g >= M) return;
    int lane4 = (threadIdx.x & 15) * 4;

    int p = row_ptr[g];
    int end = row_ptr[g + 1];

    float4 acc = make_float4(0.f, 0.f, 0.f, 0.f);
    for (; p + 2 <= end; p += 2) {
        int s0 = ssrc[p];
        int s1 = ssrc[p + 1];
        float w0 = sw[p];
        float w1 = sw[p + 1];
        float4 r0 = *reinterpret_cast<const float4*>(&support[(size_t)s0 * N_OUT + lane4]);
        float4 r1 = *reinterpret_cast<const float4*>(&support[(size_t)s1 * N_OUT + lane4]);
        acc.x = fmaf(w0, r0.x, acc.x); acc.y = fmaf(w0, r0.y, acc.y);
        acc.z = fmaf(w0, r0.z, acc.z); acc.w = fmaf(w0, r0.w, acc.w);
        acc.x = fmaf(w1, r1.x, acc.x); acc.y = fmaf(w1, r1.y, acc.y);
        acc.z = fmaf(w1, r1.z, acc.z); acc.w = fmaf(w1, r1.w, acc.w);
    }
    if (p < end) {
        int s0 = ssrc[p];
        float w0 = sw[p];
        float4 r0 = *reinterpret_cast<const float4*>(&support[(size_t)s0 * N_OUT + lane4]);
        acc.x = fmaf(w0, r0.x, acc.x); acc.y = fmaf(w0, r0.y, acc.y);
        acc.z = fmaf(w0, r0.z, acc.z); acc.w = fmaf(w0, r0.w, acc.w);
    }
    float4 o;
    o.x = fmaxf(acc.x, 0.f); o.y = fmaxf(acc.y, 0.f);
    o.z = fmaxf(acc.z, 0.f); o.w = fmaxf(acc.w, 0.f);
    *reinterpret_cast<float4*>(&out[(size_t)g * N_OUT + lane4]) = o;
}

extern "C" void kernel_launch(void* const* d_in, const int* in_sizes, int n_in,
                              void* d_out, int out_size, void* d_ws, size_t ws_size,
                              hipStream_t stream) {
    const float* x    = (const float*)d_in[0];
    const float* w    = (const float*)d_in[1];
    const int*   esrc = (const int*)d_in[2];
    const int*   edst = (const int*)d_in[3];
    const float* ew   = (const float*)d_in[4];
    float* out = (float*)d_out;

    const int M = in_sizes[0] / K_IN;   // 100000
    const int E = in_sizes[2];          // 1600000

    // ---- workspace carve-up (all 256B aligned) ----
    char* base = (char*)d_ws;
    size_t off = 0;
    float* support = (float*)(base + off);  off += (size_t)M * N_OUT * 4;  off = (off + 255) & ~(size_t)255;
    int*   row_ptr = (int*)(base + off);    off += (size_t)(M + 1) * 4;    off = (off + 255) & ~(size_t)255;
    int*   cursor  = (int*)(base + off);    off += (size_t)M * 4;          off = (off + 255) & ~(size_t)255;
    int*   bsum    = (int*)(base + off);    off += 4096;
    int*   ssrc    = (int*)(base + off);    off += (size_t)E * 4;          off = (off + 255) & ~(size_t)255;
    float* sw      = (float*)(base + off);  off += (size_t)E * 4;

    const int nb = (M + 1023) / 1024;   // scan blocks (98 <= 256)

    // support = x @ W
    gemm_kernel<<<(M + 63) / 64, 256, 0, stream>>>(x, w, support, M);

    // counting sort by dst
    hipMemsetAsync(row_ptr, 0, (size_t)(M + 1) * 4, stream);
    hist_kernel<<<(E + 255) / 256, 256, 0, stream>>>(edst, row_ptr, E);
    scan1_kernel<<<nb, 256, 0, stream>>>(row_ptr, bsum, M);
    scan2_kernel<<<1, 256, 0, stream>>>(bsum, row_ptr + M, nb);
    scan3_kernel<<<nb, 256, 0, stream>>>(row_ptr, cursor, bsum, M);
    reorder_kernel<<<(E + 255) / 256, 256, 0, stream>>>(esrc, edst, ew, cursor, ssrc, sw, E);

    // per-node register accumulate + fused ReLU
    accum_kernel<<<((M * 16) + 255) / 256, 256, 0, stream>>>(support, row_ptr, ssrc, sw, out, M);
}

// Round 3
// 410.154 us; speedup vs baseline: 3.7666x; 1.0242x over previous
//
#include <hip/hip_runtime.h>
#include <hip/hip_bf16.h>

#define K_IN 256
#define N_OUT 64

typedef __attribute__((ext_vector_type(8))) short bf16x8;
typedef __attribute__((ext_vector_type(8))) unsigned short u16x8;
typedef __attribute__((ext_vector_type(4))) float f32x4;

static __device__ __forceinline__ unsigned int pk2(float a, float b) {
    union { __hip_bfloat162 h; unsigned int u; } cv;
    cv.h = __float22bfloat162_rn(make_float2(a, b));
    return cv.u;
}

// ---- pre-pack W[256][64] into per-lane MFMA B-fragment order (bf16) --------
// frag (s=k-step 0..7, c=col-tile 0..3), lane l: elems j=0..7 at
// bpack[((s*4+c)*64+l)*8 + j] = bf16(W[s*32+(l>>4)*8+j][c*16+(l&15)])
__global__ __launch_bounds__(256) void prepack_b(const float* __restrict__ w,
                                                 unsigned short* __restrict__ bpack) {
    int t = blockIdx.x * 256 + threadIdx.x;   // 0..2047
    int s = t >> 8;
    int c = (t >> 6) & 3;
    int l = t & 63;
    u16x8 v;
    #pragma unroll
    for (int j = 0; j < 8; ++j) {
        int k = s * 32 + (l >> 4) * 8 + j;
        int n = c * 16 + (l & 15);
        union { __hip_bfloat16 h; unsigned short u; } cv;
        cv.h = __float2bfloat16(w[k * N_OUT + n]);
        v[j] = cv.u;
    }
    *reinterpret_cast<u16x8*>(&bpack[(size_t)t * 8]) = v;
}

// ---- fused: MFMA bf16 GEMM (blocks < nG) + dst-histogram (blocks >= nG) ----
// GEMM: block = 256 thr = 4 waves; 128 rows/block; per wave 32 rows x 64 cols
// = 2 row-frags x 4 col-frags of mfma_f32_16x16x32_bf16, K = 8 steps of 32.
// No LDS: A-frags straight from global (16 rows x 128B contiguous per wave),
// B-frags from prepacked L2-resident table.
__global__ __launch_bounds__(256) void gemm_hist(const float* __restrict__ x,
                                                 const unsigned short* __restrict__ bpack,
                                                 const int* __restrict__ edst,
                                                 int* __restrict__ counts,
                                                 float* __restrict__ support,
                                                 int M, int E, int nG) {
    if ((int)blockIdx.x >= nG) {
        int base = ((int)blockIdx.x - nG) * 1024 + threadIdx.x * 4;
        #pragma unroll
        for (int j = 0; j < 4; ++j) {
            int i = base + j;
            if (i < E) atomicAdd(&counts[edst[i]], 1);
        }
        return;
    }

    const int lane = threadIdx.x & 63;
    const int wave = threadIdx.x >> 6;
    const int m_base = blockIdx.x * 128 + wave * 32;
    const int lr  = lane & 15;
    const int lg4 = lane >> 4;
    const int lkf = lg4 * 8;                 // k offset (floats) within step

    f32x4 acc[2][4] = {};

    const int r0 = m_base + lr;
    const int r1 = r0 + 16;
    const float* xr0 = x + (size_t)min(r0, M - 1) * K_IN;
    const float* xr1 = x + (size_t)min(r1, M - 1) * K_IN;

    #pragma unroll
    for (int s = 0; s < 8; ++s) {
        const int k0 = s * 32 + lkf;
        float4 a0 = *reinterpret_cast<const float4*>(xr0 + k0);
        float4 a1 = *reinterpret_cast<const float4*>(xr0 + k0 + 4);
        float4 b0 = *reinterpret_cast<const float4*>(xr1 + k0);
        float4 b1 = *reinterpret_cast<const float4*>(xr1 + k0 + 4);
        union { bf16x8 v; unsigned int u[4]; } A0, A1;
        A0.u[0] = pk2(a0.x, a0.y); A0.u[1] = pk2(a0.z, a0.w);
        A0.u[2] = pk2(a1.x, a1.y); A0.u[3] = pk2(a1.z, a1.w);
        A1.u[0] = pk2(b0.x, b0.y); A1.u[1] = pk2(b0.z, b0.w);
        A1.u[2] = pk2(b1.x, b1.y); A1.u[3] = pk2(b1.z, b1.w);
        #pragma unroll
        for (int c = 0; c < 4; ++c) {
            bf16x8 B = *reinterpret_cast<const bf16x8*>(
                bpack + ((size_t)(s * 4 + c) * 64 + lane) * 8);
            acc[0][c] = __builtin_amdgcn_mfma_f32_16x16x32_bf16(A0.v, B, acc[0][c], 0, 0, 0);
            acc[1][c] = __builtin_amdgcn_mfma_f32_16x16x32_bf16(A1.v, B, acc[1][c], 0, 0, 0);
        }
    }

    // D layout: col = lane&15, row = (lane>>4)*4 + i
    #pragma unroll
    for (int rt = 0; rt < 2; ++rt) {
        #pragma unroll
        for (int i = 0; i < 4; ++i) {
            int row = m_base + rt * 16 + lg4 * 4 + i;
            if (row < M) {
                #pragma unroll
                for (int c = 0; c < 4; ++c)
                    support[(size_t)row * N_OUT + c * 16 + lr] = acc[rt][c][i];
            }
        }
    }
}

// ---------------- counting-sort scans ---------------------------------------
__global__ __launch_bounds__(256) void scan1_kernel(int* __restrict__ data,
                                                    int* __restrict__ bsum, int M) {
    __shared__ int lds[256];
    int tid = threadIdx.x;
    int base = blockIdx.x * 1024 + tid * 4;
    int v[4];
    #pragma unroll
    for (int j = 0; j < 4; ++j) v[j] = (base + j < M) ? data[base + j] : 0;
    int s = v[0] + v[1] + v[2] + v[3];
    lds[tid] = s;
    __syncthreads();
    for (int off = 1; off < 256; off <<= 1) {
        int t = (tid >= off) ? lds[tid - off] : 0;
        __syncthreads();
        lds[tid] += t;
        __syncthreads();
    }
    int excl = lds[tid] - s;
    if (tid == 255) bsum[blockIdx.x] = lds[255];
    int run = excl;
    #pragma unroll
    for (int j = 0; j < 4; ++j) {
        if (base + j < M) data[base + j] = run;
        run += v[j];
    }
}

__global__ __launch_bounds__(256) void scan2_kernel(int* __restrict__ bsum,
                                                    int* __restrict__ row_ptr_end, int nb) {
    __shared__ int lds[256];
    int tid = threadIdx.x;
    int v = (tid < nb) ? bsum[tid] : 0;
    lds[tid] = v;
    __syncthreads();
    for (int off = 1; off < 256; off <<= 1) {
        int t = (tid >= off) ? lds[tid - off] : 0;
        __syncthreads();
        lds[tid] += t;
        __syncthreads();
    }
    if (tid < nb) bsum[tid] = lds[tid] - v;
    if (tid == 255) *row_ptr_end = lds[255];
}

__global__ __launch_bounds__(256) void scan3_kernel(int* __restrict__ row_ptr,
                                                    int* __restrict__ cursor,
                                                    const int* __restrict__ bsum, int M) {
    int base = blockIdx.x * 1024 + threadIdx.x * 4;
    int add = bsum[blockIdx.x];
    #pragma unroll
    for (int j = 0; j < 4; ++j) {
        int i = base + j;
        if (i < M) {
            int r = row_ptr[i] + add;
            row_ptr[i] = r;
            cursor[i] = r;
        }
    }
}

// ---- reorder: one packed int2 (src, w-bits) scattered store per edge -------
__global__ __launch_bounds__(256) void reorder_kernel(const int* __restrict__ esrc,
                                                      const int* __restrict__ edst,
                                                      const float* __restrict__ ew,
                                                      int* __restrict__ cursor,
                                                      int2* __restrict__ edata, int E) {
    int i = blockIdx.x * blockDim.x + threadIdx.x;
    if (i >= E) return;
    int d = edst[i];
    int pos = atomicAdd(&cursor[d], 1);
    edata[pos] = make_int2(esrc[i], __float_as_int(ew[i]));
}

// ---- CSR accumulate + fused ReLU, 16 lanes per node ------------------------
__global__ __launch_bounds__(256) void accum_kernel(const float* __restrict__ support,
                                                    const int* __restrict__ row_ptr,
                                                    const int2* __restrict__ edata,
                                                    float* __restrict__ out, int M) {
    int g = (blockIdx.x * blockDim.x + threadIdx.x) >> 4;
    if (g >= M) return;
    int lane4 = (threadIdx.x & 15) * 4;

    int p = row_ptr[g];
    int end = row_ptr[g + 1];

    float4 acc = make_float4(0.f, 0.f, 0.f, 0.f);
    for (; p + 2 <= end; p += 2) {
        int2 e0 = edata[p];
        int2 e1 = edata[p + 1];
        float w0 = __int_as_float(e0.y);
        float w1 = __int_as_float(e1.y);
        float4 r0 = *reinterpret_cast<const float4*>(&support[(size_t)e0.x * N_OUT + lane4]);
        float4 r1 = *reinterpret_cast<const float4*>(&support[(size_t)e1.x * N_OUT + lane4]);
        acc.x = fmaf(w0, r0.x, acc.x); acc.y = fmaf(w0, r0.y, acc.y);
        acc.z = fmaf(w0, r0.z, acc.z); acc.w = fmaf(w0, r0.w, acc.w);
        acc.x = fmaf(w1, r1.x, acc.x); acc.y = fmaf(w1, r1.y, acc.y);
        acc.z = fmaf(w1, r1.z, acc.z); acc.w = fmaf(w1, r1.w, acc.w);
    }
    if (p < end) {
        int2 e0 = edata[p];
        float w0 = __int_as_float(e0.y);
        float4 r0 = *reinterpret_cast<const float4*>(&support[(size_t)e0.x * N_OUT + lane4]);
        acc.x = fmaf(w0, r0.x, acc.x); acc.y = fmaf(w0, r0.y, acc.y);
        acc.z = fmaf(w0, r0.z, acc.z); acc.w = fmaf(w0, r0.w, acc.w);
    }
    float4 o;
    o.x = fmaxf(acc.x, 0.f); o.y = fmaxf(acc.y, 0.f);
    o.z = fmaxf(acc.z, 0.f); o.w = fmaxf(acc.w, 0.f);
    *reinterpret_cast<float4*>(&out[(size_t)g * N_OUT + lane4]) = o;
}

extern "C" void kernel_launch(void* const* d_in, const int* in_sizes, int n_in,
                              void* d_out, int out_size, void* d_ws, size_t ws_size,
                              hipStream_t stream) {
    const float* x    = (const float*)d_in[0];
    const float* w    = (const float*)d_in[1];
    const int*   esrc = (const int*)d_in[2];
    const int*   edst = (const int*)d_in[3];
    const float* ew   = (const float*)d_in[4];
    float* out = (float*)d_out;

    const int M = in_sizes[0] / K_IN;   // 100000
    const int E = in_sizes[2];          // 1600000

    // ---- workspace carve-up (256B aligned) ----
    char* base = (char*)d_ws;
    size_t off = 0;
    float* support = (float*)(base + off);  off += (size_t)M * N_OUT * 4;  off = (off + 255) & ~(size_t)255;
    int*   row_ptr = (int*)(base + off);    off += (size_t)(M + 1) * 4;    off = (off + 255) & ~(size_t)255;
    int*   cursor  = (int*)(base + off);    off += (size_t)M * 4;          off = (off + 255) & ~(size_t)255;
    int*   bsum    = (int*)(base + off);    off += 4096;
    unsigned short* bpack = (unsigned short*)(base + off); off += 2048 * 8 * 2; off = (off + 255) & ~(size_t)255;
    int2*  edata   = (int2*)(base + off);   off += (size_t)E * 8;

    const int nG = (M + 127) / 128;        // gemm blocks (782)
    const int nH = (E + 1023) / 1024;      // hist blocks (1563)
    const int nb = (M + 1023) / 1024;      // scan blocks (98)

    prepack_b<<<8, 256, 0, stream>>>(w, bpack);
    hipMemsetAsync(row_ptr, 0, (size_t)(M + 1) * 4, stream);
    gemm_hist<<<nG + nH, 256, 0, stream>>>(x, bpack, edst, row_ptr, support, M, E, nG);
    scan1_kernel<<<nb, 256, 0, stream>>>(row_ptr, bsum, M);
    scan2_kernel<<<1, 256, 0, stream>>>(bsum, row_ptr + M, nb);
    scan3_kernel<<<nb, 256, 0, stream>>>(row_ptr, cursor, bsum, M);
    reorder_kernel<<<(E + 255) / 256, 256, 0, stream>>>(esrc, edst, ew, cursor, edata, E);
    accum_kernel<<<((M * 16) + 255) / 256, 256, 0, stream>>>(support, row_ptr, edata, out, M);
}